// Round 2
// baseline (72.690 us; speedup 1.0000x reference)
//
#include <hip/hip_runtime.h>
#include <hip/hip_bf16.h>

// ObliviousDecisionLayer on MI355X.
// Reference semantics: einsum('bj,tdk->btd') has NO shared index ->
// decisions[b,t,d] = rowsum(inputs)[b] * rowsum(dw)[t,d].
// Leaf contraction folds: bit d of leaf index l: 0 -> dec[d], 1 -> 1-dec[d].

#define NUM_TREES 256
#define DEPTH 6
#define LEAVES 64
#define BATCH 4096
#define FEATURES 256
#define BPB 4  // batch rows per block in main kernel

// ---------------- Kernel 1: row sums ----------------
// wave w < 4096: s_in[w] = sum_j inputs[w][j]
// wave w >= 4096: s_w[w-4096] = sum_k dw[(w-4096)][k]   (dw flattened [256*6][256])
__global__ __launch_bounds__(256) void rowsum_kernel(
    const float* __restrict__ inputs,   // [4096][256]
    const float* __restrict__ dw,       // [256*6][256]
    float* __restrict__ s_in,           // [4096]
    float* __restrict__ s_w)            // [1536]
{
    const int wave = (blockIdx.x * blockDim.x + threadIdx.x) >> 6;
    const int lane = threadIdx.x & 63;
    const float* src;
    float* dst;
    if (wave < BATCH) {
        src = inputs + (size_t)wave * FEATURES;
        dst = s_in + wave;
    } else {
        const int r = wave - BATCH;
        src = dw + (size_t)r * FEATURES;
        dst = s_w + r;
    }
    // 64 lanes x float4 = 256 elements
    float4 v = reinterpret_cast<const float4*>(src)[lane];
    float s = (v.x + v.y) + (v.z + v.w);
#pragma unroll
    for (int off = 32; off > 0; off >>= 1)
        s += __shfl_down(s, off);
    if (lane == 0) *dst = s;
}

// ---------------- Kernel 2: per-(b,t) evaluation + tree-mean ----------------
__global__ __launch_bounds__(256) void forest_kernel(
    const float* __restrict__ thr,      // [256][6]
    const float* __restrict__ leaf,     // [256][64]
    const float* __restrict__ s_in,     // [4096]
    const float* __restrict__ s_w,      // [256][6]
    float* __restrict__ out)            // [4096]
{
    const int t  = threadIdx.x;         // tree index, 0..255
    const int b0 = blockIdx.x * BPB;    // first batch row of this block

    // Per-tree constants
    float sw[DEPTH], th[DEPTH];
#pragma unroll
    for (int d = 0; d < DEPTH; ++d) {
        sw[d] = s_w[t * DEPTH + d];
        th[d] = thr[t * DEPTH + d];
    }
    float lf[LEAVES];
    const float4* lp = reinterpret_cast<const float4*>(leaf + (size_t)t * LEAVES);
#pragma unroll
    for (int i = 0; i < LEAVES / 4; ++i) {
        float4 v = lp[i];
        lf[4 * i + 0] = v.x; lf[4 * i + 1] = v.y;
        lf[4 * i + 2] = v.z; lf[4 * i + 3] = v.w;
    }

    float res[BPB];
#pragma unroll
    for (int bi = 0; bi < BPB; ++bi) {
        const float si = s_in[b0 + bi];
        float dec[DEPTH];
#pragma unroll
        for (int d = 0; d < DEPTH; ++d) {
            const float x = fmaf(si, sw[d], th[d]);
            dec[d] = 1.0f / (1.0f + __expf(-x));  // sigmoid
        }
        // Fold leaves over bits 5..0: bit==0 picks dec[d], bit==1 picks 1-dec[d].
        // m[i] = m[i+half]*(1-dec) + m[i]*dec = fma(dec, m[i]-m[i+half], m[i+half])
        float m[32];
#pragma unroll
        for (int i = 0; i < 32; ++i) m[i] = fmaf(dec[5], lf[i] - lf[i + 32], lf[i + 32]);
#pragma unroll
        for (int i = 0; i < 16; ++i) m[i] = fmaf(dec[4], m[i] - m[i + 16], m[i + 16]);
#pragma unroll
        for (int i = 0; i < 8; ++i)  m[i] = fmaf(dec[3], m[i] - m[i + 8],  m[i + 8]);
#pragma unroll
        for (int i = 0; i < 4; ++i)  m[i] = fmaf(dec[2], m[i] - m[i + 4],  m[i + 4]);
#pragma unroll
        for (int i = 0; i < 2; ++i)  m[i] = fmaf(dec[1], m[i] - m[i + 2],  m[i + 2]);
        res[bi] = fmaf(dec[0], m[0] - m[1], m[1]);
    }

    // Reduce res[bi] over 256 trees (4 waves) -> mean
    __shared__ float red[4][BPB];
    const int lane = t & 63;
    const int wv   = t >> 6;
#pragma unroll
    for (int bi = 0; bi < BPB; ++bi) {
        float v = res[bi];
#pragma unroll
        for (int off = 32; off > 0; off >>= 1)
            v += __shfl_down(v, off);
        if (lane == 0) red[wv][bi] = v;
    }
    __syncthreads();
    if (t < BPB) {
        const float v = red[0][t] + red[1][t] + red[2][t] + red[3][t];
        out[b0 + t] = v * (1.0f / (float)NUM_TREES);
    }
}

extern "C" void kernel_launch(void* const* d_in, const int* in_sizes, int n_in,
                              void* d_out, int out_size, void* d_ws, size_t ws_size,
                              hipStream_t stream) {
    const float* inputs = (const float*)d_in[0];  // [4096][256]
    const float* dw     = (const float*)d_in[1];  // [256][6][256]
    const float* thr    = (const float*)d_in[2];  // [256][6]
    const float* leaf   = (const float*)d_in[3];  // [256][64]
    float* out = (float*)d_out;                   // [4096]

    float* s_in = (float*)d_ws;                   // 4096 floats
    float* s_w  = s_in + BATCH;                   // 1536 floats

    // Kernel 1: 4096 + 1536 = 5632 waves, 4 waves/block -> 1408 blocks
    const int total_waves = BATCH + NUM_TREES * DEPTH;
    rowsum_kernel<<<total_waves / 4, 256, 0, stream>>>(inputs, dw, s_in, s_w);

    // Kernel 2: 4096 / BPB blocks of 256 threads
    forest_kernel<<<BATCH / BPB, 256, 0, stream>>>(thr, leaf, s_in, s_w, out);
}

// Round 3
// 69.627 us; speedup vs baseline: 1.0440x; 1.0440x over previous
//
#include <hip/hip_runtime.h>
#include <hip/hip_bf16.h>

// ObliviousDecisionLayer on MI355X.
// Reference semantics: einsum('bj,tdk->btd') has NO shared index ->
// decisions[b,t,d] = rowsum(inputs)[b] * rowsum(dw)[t,d].
// Leaf contraction folds: bit d of leaf index l: 0 -> dec[d], 1 -> 1-dec[d].
//
// R3 change: forest kernel previously read leaf[t*64+..] (64 lanes at 256B
// stride = 64 cache lines per load instr -> L1 scatter serialization).
// Prep kernel now transposes leaf/thresholds/weight-sums into tree-major
// layouts in ws so ALL forest loads are wave-coalesced.

#define NUM_TREES 256
#define DEPTH 6
#define LEAVES 64
#define BATCH 4096
#define FEATURES 256
#define BPB 8  // batch rows per forest block

// ws layout (floats):
//   s_in    @ 0      [4096]
//   sw_t    @ 4096   [6][256]   sw_t[d][t] = rowsum(dw[t][d][:])
//   th_t    @ 5632   [6][256]   th_t[d][t] = thr[t][d]
//   leaf_t4 @ 7168   [16][256][4]  leaf_t4[c][t] = leaf[t][4c..4c+3]
#define WS_SIN  0
#define WS_SWT  4096
#define WS_THT  5632
#define WS_LF4  7168

// ---------------- Kernel 1: row sums + transposes ----------------
// waves 0..4095      : s_in[w] = sum_j inputs[w][j]
// waves 4096..5631   : r=w-4096 (=t*6+d): sw_t[d][t] = sum_k dw[r][k]
// waves 5632..5695   : leaf transpose (float4 chunks)
// waves 5696..5719   : threshold transpose
__global__ __launch_bounds__(256) void prep_kernel(
    const float* __restrict__ inputs,   // [4096][256]
    const float* __restrict__ dw,       // [1536][256]
    const float* __restrict__ thr,      // [256][6]
    const float* __restrict__ leaf,     // [256][64]
    float* __restrict__ ws)
{
    const int gw   = (blockIdx.x * blockDim.x + threadIdx.x) >> 6;
    const int lane = threadIdx.x & 63;

    if (gw < BATCH + NUM_TREES * DEPTH) {
        // row-sum of a 256-float row
        const float* src;
        float* dst;
        if (gw < BATCH) {
            src = inputs + (size_t)gw * FEATURES;
            dst = ws + WS_SIN + gw;
        } else {
            const int r = gw - BATCH;        // r = t*6 + d
            const int t = r / DEPTH;
            const int d = r - t * DEPTH;
            src = dw + (size_t)r * FEATURES;
            dst = ws + WS_SWT + d * NUM_TREES + t;
        }
        float4 v = reinterpret_cast<const float4*>(src)[lane];
        float s = (v.x + v.y) + (v.z + v.w);
#pragma unroll
        for (int off = 32; off > 0; off >>= 1)
            s += __shfl_down(s, off);
        if (lane == 0) *dst = s;
    } else if (gw < BATCH + NUM_TREES * DEPTH + 64) {
        // leaf transpose: wave j handles chunk c=j>>2, trees t=(j&3)*64+lane
        const int j = gw - (BATCH + NUM_TREES * DEPTH);
        const int c = j >> 2;
        const int t = ((j & 3) << 6) | lane;
        float4 v = reinterpret_cast<const float4*>(leaf)[t * (LEAVES / 4) + c];
        reinterpret_cast<float4*>(ws + WS_LF4)[c * NUM_TREES + t] = v;
    } else {
        // threshold transpose: 24 waves cover 1536 elements
        const int j = gw - (BATCH + NUM_TREES * DEPTH + 64);
        const int idx = j * 64 + lane;       // = t*6 + d
        const int t = idx / DEPTH;
        const int d = idx - t * DEPTH;
        ws[WS_THT + d * NUM_TREES + t] = thr[idx];
    }
}

// ---------------- Kernel 2: per-(b,t) evaluation + tree-mean ----------------
__global__ __launch_bounds__(256) void forest_kernel(
    const float* __restrict__ ws,
    float* __restrict__ out)            // [4096]
{
    const int t  = threadIdx.x;         // tree index, 0..255
    const int b0 = blockIdx.x * BPB;    // first batch row of this block

    // Per-tree constants — ALL loads wave-coalesced (stride-1 in t)
    float sw[DEPTH], th[DEPTH];
#pragma unroll
    for (int d = 0; d < DEPTH; ++d) {
        sw[d] = ws[WS_SWT + d * NUM_TREES + t];
        th[d] = ws[WS_THT + d * NUM_TREES + t];
    }
    float lf[LEAVES];
    const float4* lp = reinterpret_cast<const float4*>(ws + WS_LF4);
#pragma unroll
    for (int c = 0; c < LEAVES / 4; ++c) {
        float4 v = lp[c * NUM_TREES + t];   // 64 lanes x 16B consecutive = 1KB
        lf[4 * c + 0] = v.x; lf[4 * c + 1] = v.y;
        lf[4 * c + 2] = v.z; lf[4 * c + 3] = v.w;
    }

    float res[BPB];
#pragma unroll
    for (int bi = 0; bi < BPB; ++bi) {
        const float si = ws[WS_SIN + b0 + bi];  // block-uniform -> scalar load
        float dec[DEPTH];
#pragma unroll
        for (int d = 0; d < DEPTH; ++d) {
            const float x = fmaf(si, sw[d], th[d]);
            dec[d] = 1.0f / (1.0f + __expf(-x));  // sigmoid
        }
        // Fold leaves over bits 5..0: bit==0 picks dec[d], bit==1 picks 1-dec[d].
        float m[32];
#pragma unroll
        for (int i = 0; i < 32; ++i) m[i] = fmaf(dec[5], lf[i] - lf[i + 32], lf[i + 32]);
#pragma unroll
        for (int i = 0; i < 16; ++i) m[i] = fmaf(dec[4], m[i] - m[i + 16], m[i + 16]);
#pragma unroll
        for (int i = 0; i < 8; ++i)  m[i] = fmaf(dec[3], m[i] - m[i + 8],  m[i + 8]);
#pragma unroll
        for (int i = 0; i < 4; ++i)  m[i] = fmaf(dec[2], m[i] - m[i + 4],  m[i + 4]);
#pragma unroll
        for (int i = 0; i < 2; ++i)  m[i] = fmaf(dec[1], m[i] - m[i + 2],  m[i + 2]);
        res[bi] = fmaf(dec[0], m[0] - m[1], m[1]);
    }

    // Reduce res[bi] over 256 trees (4 waves) -> mean
    __shared__ float red[4][BPB];
    const int lane = t & 63;
    const int wv   = t >> 6;
#pragma unroll
    for (int bi = 0; bi < BPB; ++bi) {
        float v = res[bi];
#pragma unroll
        for (int off = 32; off > 0; off >>= 1)
            v += __shfl_down(v, off);
        if (lane == 0) red[wv][bi] = v;
    }
    __syncthreads();
    if (t < BPB) {
        const float v = red[0][t] + red[1][t] + red[2][t] + red[3][t];
        out[b0 + t] = v * (1.0f / (float)NUM_TREES);
    }
}

extern "C" void kernel_launch(void* const* d_in, const int* in_sizes, int n_in,
                              void* d_out, int out_size, void* d_ws, size_t ws_size,
                              hipStream_t stream) {
    const float* inputs = (const float*)d_in[0];  // [4096][256]
    const float* dw     = (const float*)d_in[1];  // [256][6][256]
    const float* thr    = (const float*)d_in[2];  // [256][6]
    const float* leaf   = (const float*)d_in[3];  // [256][64]
    float* out = (float*)d_out;                   // [4096]
    float* ws  = (float*)d_ws;

    // prep: 4096 + 1536 + 64 + 24 = 5720 waves, 4 waves/block -> 1430 blocks
    prep_kernel<<<1430, 256, 0, stream>>>(inputs, dw, thr, leaf, ws);

    // forest: 4096 / BPB = 512 blocks of 256 threads
    forest_kernel<<<BATCH / BPB, 256, 0, stream>>>(ws, out);
}